// Round 5
// baseline (769.723 us; speedup 1.0000x reference)
//
#include <hip/hip_runtime.h>
#include <hip/hip_bf16.h>
#include <stdint.h>

#define NUM_EXPERTS 32
#define HIDDEN 2048
#define INTER 2816
#define HALFI 1408
#define TOKENS 1024
#define TOPK 8
#define TA (TOKENS*TOPK)
#define CAP 512
#define BK 64

typedef float f32x4 __attribute__((ext_vector_type(4)));
typedef __bf16 bf16x8 __attribute__((ext_vector_type(8)));

__device__ __forceinline__ uint32_t swz(uint32_t row, uint32_t colbyte) {
  // 128-byte LDS rows (64 bf16); XOR row bits into 16B-slot bits -> conflict-free ds_read_b128
  return row * 128u + (colbyte ^ ((row & 7u) << 4));
}
__device__ __forceinline__ uint32_t pk2(float a, float b) {
  union { __bf16 h[2]; uint32_t u; } c;
  c.h[0] = (__bf16)a; c.h[1] = (__bf16)b; return c.u;
}
__device__ __forceinline__ uint16_t bf16b(float a) {
  union { __bf16 h; uint16_t u; } c; c.h = (__bf16)a; return c.u;
}

// ---------------- routing ----------------
__global__ void route_count(const int* __restrict__ tkidx, int* __restrict__ offs) {
  __shared__ int cnt[NUM_EXPERTS];
  int tid = threadIdx.x;
  if (tid < NUM_EXPERTS) cnt[tid] = 0;
  __syncthreads();
  for (int i = tid; i < TA; i += 256) atomicAdd(&cnt[tkidx[i]], 1);
  __syncthreads();
  if (tid == 0) {
    int acc = 0;
    for (int e = 0; e < NUM_EXPERTS; ++e) { offs[e] = acc; acc += cnt[e]; }
    offs[NUM_EXPERTS] = acc;
  }
}

// one wave per expert; stable rank via ballot; also emits inverse map i->srow
__global__ void route_build(const int* __restrict__ tkidx, const float* __restrict__ tkw,
                            const int* __restrict__ offs,
                            int* __restrict__ tok_of_row, int* __restrict__ inv) {
  int e = blockIdx.x;
  int lane = threadIdx.x;
  int base = offs[e];
  int run = 0;
  for (int c0 = 0; c0 < TA; c0 += 64) {
    int i = c0 + lane;
    bool p = (tkidx[i] == e);
    unsigned long long m = __ballot(p);
    if (p) {
      int rank = run + __popcll(m & ((1ull << lane) - 1ull));
      if (rank < CAP) {
        tok_of_row[base + rank] = i >> 3;   // TOPK = 8
        inv[i] = base + rank;
      } else {
        inv[i] = -1;                        // capacity-dropped
      }
    }
    run += __popcll(m);
  }
}

// ---------------- pre-pass: permuted A panel in bf16 ----------------
__global__ __launch_bounds__(256) void perm_cast(
    const float* __restrict__ hidden, const int* __restrict__ tok_of_row,
    uint16_t* __restrict__ A1_perm) {
  const int srow = blockIdx.x;
  const int tok = tok_of_row[srow] & (TOKENS - 1);   // clamp vs poisoned ws
  const float* src = hidden + (size_t)tok * HIDDEN + threadIdx.x * 8;
  f32x4 a = *(const f32x4*)(src);
  f32x4 b = *(const f32x4*)(src + 4);
  uint4 v;
  v.x = pk2(a.x, a.y); v.y = pk2(a.z, a.w);
  v.z = pk2(b.x, b.y); v.w = pk2(b.z, b.w);
  *(uint4*)(A1_perm + (size_t)srow * HIDDEN + threadIdx.x * 8) = v;
}

// ---------------- GEMM1: h = A1 * W1^T, a = silu(gate)*up -> A_ws (bf16) ----------------
// BM=128, BN=128 (64 gate + 64 up paired per wave), BK=64, 256 threads (2M x 2N waves).
// Depth-2 register prefetch: tile t+2 issued at step t, written at step t+1.
__global__ __launch_bounds__(256, 2) void moe_gemm1(
    const uint16_t* __restrict__ A1_perm, const float* __restrict__ w1,
    const int* __restrict__ offs, uint16_t* __restrict__ A_ws)
{
  const int s = blockIdx.x;            // 2816 = 352*8
  const int xcd = s & 7, kk = s >> 3;  // kk: 0..351
  const int mt = kk & 3, pl = kk >> 2; // mt: 4 M-tiles of 128
  const int pair = pl * 8 + xcd;       // 0..703
  const int e = pair / 22, ns = pair % 22;

  const int off = offs[e];
  const int cnt = min(offs[e + 1] - off, CAP);
  if (mt * 128 >= cnt) return;

  __shared__ __align__(16) char lds[65536];  // A dbuf 2x16KB @0, B dbuf 2x16KB @32768
  const int tid = threadIdx.x;

  // A staging: rows j*32 + (tid>>3) (j<4), 16B (8 bf16) at chunk (tid&7)
  size_t aoff[4];
  uint32_t wa[4];
#pragma unroll
  for (int j = 0; j < 4; ++j) {
    int row = j * 32 + (tid >> 3);
    int srow = min(off + mt * 128 + row, TA - 1);   // rows >= cnt feed dead lanes only
    aoff[j] = (size_t)srow * HIDDEN + (tid & 7) * 8;
    wa[j] = swz((uint32_t)row, (uint32_t)(tid & 7) * 16);
  }
  // B staging: LDS row r = j*16 + (tid>>4) (j<8); q=(r>>5)&1 gate/up, i=r&31, wn=r>>6
  const float* bp[8];
  uint32_t wb[8];
#pragma unroll
  for (int j = 0; j < 8; ++j) {
    int r = j * 16 + (tid >> 4);
    int wn = r >> 6, q = (r >> 5) & 1, i = r & 31;
    int col = q * HALFI + ns * 64 + wn * 32 + i;
    bp[j] = w1 + ((size_t)e * INTER + col) * HIDDEN + (tid & 15) * 4;
    wb[j] = swz((uint32_t)r, (uint32_t)(tid & 15) * 8);
  }

  uint4 raE[4], raO[4];
  f32x4 rbE[8], rbO[8];

  const int lane = tid & 63, wv = tid >> 6;
  const int wm = (wv >> 1) * 64;          // M half
  const int wn = wv & 1;                  // N half (B LDS rows wn*64..)
  const int fr = lane & 15, fq = lane >> 4;
  const bool active = (mt * 128 + wm) < cnt;

  f32x4 acc[4][4];
#pragma unroll
  for (int i = 0; i < 4; ++i)
#pragma unroll
    for (int j = 0; j < 4; ++j) acc[i][j] = (f32x4)0.f;

  auto LOADE = [&](int k0) {
#pragma unroll
    for (int j = 0; j < 4; ++j) raE[j] = *(const uint4*)(A1_perm + aoff[j] + k0);
#pragma unroll
    for (int j = 0; j < 8; ++j) rbE[j] = *(const f32x4*)(bp[j] + k0);
  };
  auto LOADO = [&](int k0) {
#pragma unroll
    for (int j = 0; j < 4; ++j) raO[j] = *(const uint4*)(A1_perm + aoff[j] + k0);
#pragma unroll
    for (int j = 0; j < 8; ++j) rbO[j] = *(const f32x4*)(bp[j] + k0);
  };
  auto WRITEE = [&](int buf) {
    char* pa = lds + buf * 16384;
    char* pb = lds + 32768 + buf * 16384;
#pragma unroll
    for (int j = 0; j < 4; ++j) *(uint4*)(pa + wa[j]) = raE[j];
#pragma unroll
    for (int j = 0; j < 8; ++j) {
      uint2 v; v.x = pk2(rbE[j].x, rbE[j].y); v.y = pk2(rbE[j].z, rbE[j].w);
      *(uint2*)(pb + wb[j]) = v;
    }
  };
  auto WRITEO = [&](int buf) {
    char* pa = lds + buf * 16384;
    char* pb = lds + 32768 + buf * 16384;
#pragma unroll
    for (int j = 0; j < 4; ++j) *(uint4*)(pa + wa[j]) = raO[j];
#pragma unroll
    for (int j = 0; j < 8; ++j) {
      uint2 v; v.x = pk2(rbO[j].x, rbO[j].y); v.y = pk2(rbO[j].z, rbO[j].w);
      *(uint2*)(pb + wb[j]) = v;
    }
  };
  auto MFMA = [&](int buf) {
    const char* pa = lds + buf * 16384;
    const char* pb = lds + 32768 + buf * 16384;
#pragma unroll
    for (int ks = 0; ks < 2; ++ks) {
      const uint32_t kb = (uint32_t)(ks * 64 + fq * 16);
      bf16x8 af[4], bf[4];
#pragma unroll
      for (int mf = 0; mf < 4; ++mf)
        af[mf] = *(const bf16x8*)(pa + swz((uint32_t)(wm + mf * 16 + fr), kb));
#pragma unroll
      for (int nf = 0; nf < 4; ++nf)
        bf[nf] = *(const bf16x8*)(pb + swz((uint32_t)(wn * 64 + nf * 16 + fr), kb));
#pragma unroll
      for (int mf = 0; mf < 4; ++mf)
#pragma unroll
        for (int nf = 0; nf < 4; ++nf)
          acc[mf][nf] = __builtin_amdgcn_mfma_f32_16x16x32_bf16(af[mf], bf[nf], acc[mf][nf], 0, 0, 0);
    }
  };

  const int NT = HIDDEN / BK;  // 32 (even)
  LOADE(0);
  WRITEE(0);          // waits set E once (prologue)
  LOADO(BK);          // tile 1 in flight
  int cur = 0;
  for (int t = 0; t < NT; t += 2) {
    // even step: compute tile t, write tile t+1 (set O), issue tile t+2 (set E)
    __syncthreads();
    if (t + 2 < NT) LOADE((t + 2) * BK);
    if (active) MFMA(cur);
    if (t + 1 < NT) WRITEO(cur ^ 1);
    cur ^= 1;
    // odd step: compute tile t+1, write tile t+2 (set E), issue tile t+3 (set O)
    __syncthreads();
    if (t + 3 < NT) LOADO((t + 3) * BK);
    if (t + 1 < NT && active) MFMA(cur);
    if (t + 2 < NT) WRITEE(cur ^ 1);
    cur ^= 1;
  }

  // epilogue: silu(gate)*up -> bf16 A_ws ; gate nf 0,1 pairs with up nf 2,3
  if (active) {
#pragma unroll
    for (int mf = 0; mf < 4; ++mf) {
#pragma unroll
      for (int r = 0; r < 4; ++r) {
        int grow = mt * 128 + wm + mf * 16 + fq * 4 + r;
        if (grow < cnt) {
          size_t srow = (size_t)(off + grow);
#pragma unroll
          for (int nf = 0; nf < 2; ++nf) {
            float g = acc[mf][nf][r];
            float u = acc[mf][nf + 2][r];
            float val = g / (1.f + __expf(-g)) * u;
            A_ws[srow * HALFI + ns * 64 + wn * 32 + nf * 16 + fr] = bf16b(val);
          }
        }
      }
    }
  }
}

// ---------------- GEMM2: Y = A_ws * W2^T (per-assignment fp32, no atomics) ----------------
__global__ __launch_bounds__(256, 2) void moe_gemm2(
    const uint16_t* __restrict__ A_ws, const float* __restrict__ w2,
    const int* __restrict__ offs, float* __restrict__ Y)
{
  const int s = blockIdx.x;            // 2048 = 256*8
  const int xcd = s & 7, kk = s >> 3;  // kk: 0..255
  const int mt = kk & 3, pl = kk >> 2; // pl: 0..63
  const int pair = pl * 8 + xcd;       // 0..511
  const int e = pair >> 4, ns = pair & 15;

  const int off = offs[e];
  const int cnt = min(offs[e + 1] - off, CAP);
  if (mt * 128 >= cnt) return;

  __shared__ __align__(16) char lds[65536];
  const int tid = threadIdx.x;

  size_t aoff[4];
  uint32_t wa[4];
#pragma unroll
  for (int j = 0; j < 4; ++j) {
    int row = j * 32 + (tid >> 3);
    int srow = min(off + mt * 128 + row, TA - 1);
    aoff[j] = (size_t)srow * HALFI + (tid & 7) * 8;
    wa[j] = swz((uint32_t)row, (uint32_t)(tid & 7) * 16);
  }
  const float* bp[8];
  uint32_t wb[8];
#pragma unroll
  for (int j = 0; j < 8; ++j) {
    int r = j * 16 + (tid >> 4);
    bp[j] = w2 + ((size_t)e * HIDDEN + ns * 128 + r) * HALFI + (tid & 15) * 4;
    wb[j] = swz((uint32_t)r, (uint32_t)(tid & 15) * 8);
  }

  uint4 raE[4], raO[4];
  f32x4 rbE[8], rbO[8];

  const int lane = tid & 63, wv = tid >> 6;
  const int wm = (wv >> 1) * 64;
  const int wn = wv & 1;
  const int fr = lane & 15, fq = lane >> 4;
  const bool active = (mt * 128 + wm) < cnt;

  f32x4 acc[4][4];
#pragma unroll
  for (int i = 0; i < 4; ++i)
#pragma unroll
    for (int j = 0; j < 4; ++j) acc[i][j] = (f32x4)0.f;

  auto LOADE = [&](int k0) {
#pragma unroll
    for (int j = 0; j < 4; ++j) raE[j] = *(const uint4*)(A_ws + aoff[j] + k0);
#pragma unroll
    for (int j = 0; j < 8; ++j) rbE[j] = *(const f32x4*)(bp[j] + k0);
  };
  auto LOADO = [&](int k0) {
#pragma unroll
    for (int j = 0; j < 4; ++j) raO[j] = *(const uint4*)(A_ws + aoff[j] + k0);
#pragma unroll
    for (int j = 0; j < 8; ++j) rbO[j] = *(const f32x4*)(bp[j] + k0);
  };
  auto WRITEE = [&](int buf) {
    char* pa = lds + buf * 16384;
    char* pb = lds + 32768 + buf * 16384;
#pragma unroll
    for (int j = 0; j < 4; ++j) *(uint4*)(pa + wa[j]) = raE[j];
#pragma unroll
    for (int j = 0; j < 8; ++j) {
      uint2 v; v.x = pk2(rbE[j].x, rbE[j].y); v.y = pk2(rbE[j].z, rbE[j].w);
      *(uint2*)(pb + wb[j]) = v;
    }
  };
  auto WRITEO = [&](int buf) {
    char* pa = lds + buf * 16384;
    char* pb = lds + 32768 + buf * 16384;
#pragma unroll
    for (int j = 0; j < 4; ++j) *(uint4*)(pa + wa[j]) = raO[j];
#pragma unroll
    for (int j = 0; j < 8; ++j) {
      uint2 v; v.x = pk2(rbO[j].x, rbO[j].y); v.y = pk2(rbO[j].z, rbO[j].w);
      *(uint2*)(pb + wb[j]) = v;
    }
  };
  auto MFMA = [&](int buf) {
    const char* pa = lds + buf * 16384;
    const char* pb = lds + 32768 + buf * 16384;
#pragma unroll
    for (int ks = 0; ks < 2; ++ks) {
      const uint32_t kb = (uint32_t)(ks * 64 + fq * 16);
      bf16x8 af[4], bf[4];
#pragma unroll
      for (int mf = 0; mf < 4; ++mf)
        af[mf] = *(const bf16x8*)(pa + swz((uint32_t)(wm + mf * 16 + fr), kb));
#pragma unroll
      for (int nf = 0; nf < 4; ++nf)
        bf[nf] = *(const bf16x8*)(pb + swz((uint32_t)(wn * 64 + nf * 16 + fr), kb));
#pragma unroll
      for (int mf = 0; mf < 4; ++mf)
#pragma unroll
        for (int nf = 0; nf < 4; ++nf)
          acc[mf][nf] = __builtin_amdgcn_mfma_f32_16x16x32_bf16(af[mf], bf[nf], acc[mf][nf], 0, 0, 0);
    }
  };

  const int NT = HALFI / BK;  // 22 (even)
  LOADE(0);
  WRITEE(0);
  LOADO(BK);
  int cur = 0;
  for (int t = 0; t < NT; t += 2) {
    __syncthreads();
    if (t + 2 < NT) LOADE((t + 2) * BK);
    if (active) MFMA(cur);
    if (t + 1 < NT) WRITEO(cur ^ 1);
    cur ^= 1;
    __syncthreads();
    if (t + 3 < NT) LOADO((t + 3) * BK);
    if (t + 1 < NT && active) MFMA(cur);
    if (t + 2 < NT) WRITEE(cur ^ 1);
    cur ^= 1;
  }

  if (active) {
#pragma unroll
    for (int mf = 0; mf < 4; ++mf) {
#pragma unroll
      for (int r = 0; r < 4; ++r) {
        int grow = mt * 128 + wm + mf * 16 + fq * 4 + r;
        if (grow < cnt) {
          size_t srow = (size_t)(off + grow);
          float* po = Y + srow * HIDDEN + ns * 128 + wn * 64 + fr;
#pragma unroll
          for (int nf = 0; nf < 4; ++nf)
            po[nf * 16] = acc[mf][nf][r];
        }
      }
    }
  }
}

// ---------------- combine: out[tok] = sum_slot w[tok,slot] * Y[inv[tok,slot]] ----------------
__global__ __launch_bounds__(256) void combine(
    const float* __restrict__ Y, const float* __restrict__ tkw,
    const int* __restrict__ inv, float* __restrict__ out) {
  const int tok = blockIdx.x;
  const int c = threadIdx.x * 8;
  f32x4 s0 = (f32x4)0.f, s1 = (f32x4)0.f;
#pragma unroll
  for (int slot = 0; slot < TOPK; ++slot) {
    int srow = inv[tok * TOPK + slot];
    if (srow >= 0) {
      float w = tkw[tok * TOPK + slot];
      const float* y = Y + (size_t)srow * HIDDEN + c;
      f32x4 a = *(const f32x4*)y;
      f32x4 b = *(const f32x4*)(y + 4);
      s0 += w * a;
      s1 += w * b;
    }
  }
  float* po = out + (size_t)tok * HIDDEN + c;
  *(f32x4*)po = s0;
  *(f32x4*)(po + 4) = s1;
}

extern "C" void kernel_launch(void* const* d_in, const int* in_sizes, int n_in,
                              void* d_out, int out_size, void* d_ws, size_t ws_size,
                              hipStream_t stream) {
  const float* hidden = (const float*)d_in[0];
  const float* topk_w = (const float*)d_in[1];
  const float* w1     = (const float*)d_in[2];
  const float* w2     = (const float*)d_in[3];
  const int*   tkidx  = (const int*)d_in[4];

  char* ws = (char*)d_ws;
  int*      offs       = (int*)ws;                          // 33 ints
  int*      tok_of_row = (int*)(ws + 1024);                 // TA ints
  int*      inv        = (int*)(ws + 1024 + 4 * TA);        // TA ints
  uint16_t* A1_perm    = (uint16_t*)(ws + 131072);          // TA x 2048 bf16 (33.5 MB)
  uint16_t* A_ws       = (uint16_t*)(ws + 131072 + (size_t)TA * HIDDEN * 2);   // TA x 1408 bf16
  float*    Y          = (float*)(ws + 131072 + (size_t)TA * (HIDDEN + HALFI) * 2);  // TA x 2048 f32
  float*    out        = (float*)d_out;

  route_count<<<1, 256, 0, stream>>>(tkidx, offs);
  route_build<<<NUM_EXPERTS, 64, 0, stream>>>(tkidx, topk_w, offs, tok_of_row, inv);
  perm_cast<<<TA, 256, 0, stream>>>(hidden, tok_of_row, A1_perm);
  moe_gemm1<<<dim3(22 * 32 * 4), 256, 0, stream>>>(A1_perm, w1, offs, A_ws);
  moe_gemm2<<<dim3(16 * 32 * 4), 256, 0, stream>>>(A_ws, w2, offs, Y);
  combine<<<TOKENS, 256, 0, stream>>>(Y, topk_w, inv, out);
}

// Round 6
// 601.362 us; speedup vs baseline: 1.2800x; 1.2800x over previous
//
#include <hip/hip_runtime.h>
#include <hip/hip_bf16.h>
#include <stdint.h>

#define NUM_EXPERTS 32
#define HIDDEN 2048
#define INTER 2816
#define HALFI 1408
#define TOKENS 1024
#define TOPK 8
#define TA (TOKENS*TOPK)
#define CAP 512
#define BK 32

typedef float f32x4 __attribute__((ext_vector_type(4)));
typedef __bf16 bf16x8 __attribute__((ext_vector_type(8)));
typedef unsigned int u32;
typedef __attribute__((address_space(3))) u32 lds_u32;
typedef __attribute__((address_space(1))) const u32 glb_u32;

__device__ __forceinline__ void gload16(const void* g, void* l) {
  // async global->LDS DMA, 16B per lane, LDS dest = wave base + lane*16 (linear)
  __builtin_amdgcn_global_load_lds((glb_u32*)g, (lds_u32*)l, 16, 0, 0);
}
__device__ __forceinline__ uint32_t pk2(float a, float b) {
  union { __bf16 h[2]; uint32_t u; } c;
  c.h[0] = (__bf16)a; c.h[1] = (__bf16)b; return c.u;
}
__device__ __forceinline__ uint16_t bf16b(float a) {
  union { __bf16 h; uint16_t u; } c; c.h = (__bf16)a; return c.u;
}
__device__ __forceinline__ bf16x8 cvt8(f32x4 lo, f32x4 hi) {
  bf16x8 r;
  r[0] = (__bf16)lo.x; r[1] = (__bf16)lo.y; r[2] = (__bf16)lo.z; r[3] = (__bf16)lo.w;
  r[4] = (__bf16)hi.x; r[5] = (__bf16)hi.y; r[6] = (__bf16)hi.z; r[7] = (__bf16)hi.w;
  return r;
}

// ---------------- routing ----------------
__global__ void route_count(const int* __restrict__ tkidx, int* __restrict__ offs) {
  __shared__ int cnt[NUM_EXPERTS];
  int tid = threadIdx.x;
  if (tid < NUM_EXPERTS) cnt[tid] = 0;
  __syncthreads();
  for (int i = tid; i < TA; i += 256) atomicAdd(&cnt[tkidx[i]], 1);
  __syncthreads();
  if (tid == 0) {
    int acc = 0;
    for (int e = 0; e < NUM_EXPERTS; ++e) { offs[e] = acc; acc += cnt[e]; }
    offs[NUM_EXPERTS] = acc;
  }
}

__global__ void route_build(const int* __restrict__ tkidx, const float* __restrict__ tkw,
                            const int* __restrict__ offs,
                            int* __restrict__ tok_of_row, int* __restrict__ inv) {
  int e = blockIdx.x;
  int lane = threadIdx.x;
  int base = offs[e];
  int run = 0;
  for (int c0 = 0; c0 < TA; c0 += 64) {
    int i = c0 + lane;
    bool p = (tkidx[i] == e);
    unsigned long long m = __ballot(p);
    if (p) {
      int rank = run + __popcll(m & ((1ull << lane) - 1ull));
      if (rank < CAP) {
        tok_of_row[base + rank] = i >> 3;   // TOPK = 8
        inv[i] = base + rank;
      } else {
        inv[i] = -1;                        // capacity-dropped
      }
    }
    run += __popcll(m);
  }
}

// ---------------- pre-pass: permuted A panel in bf16 ----------------
__global__ __launch_bounds__(256) void perm_cast(
    const float* __restrict__ hidden, const int* __restrict__ tok_of_row,
    uint16_t* __restrict__ A1_perm) {
  const int srow = blockIdx.x;
  const int tok = tok_of_row[srow] & (TOKENS - 1);   // clamp vs poisoned ws
  const float* src = hidden + (size_t)tok * HIDDEN + threadIdx.x * 8;
  f32x4 a = *(const f32x4*)(src);
  f32x4 b = *(const f32x4*)(src + 4);
  uint4 v;
  v.x = pk2(a.x, a.y); v.y = pk2(a.z, a.w);
  v.z = pk2(b.x, b.y); v.w = pk2(b.z, b.w);
  *(uint4*)(A1_perm + (size_t)srow * HIDDEN + threadIdx.x * 8) = v;
}

// ---------------- GEMM1: h = A1 * W1^T, silu(gate)*up -> A_ws (bf16) ----------------
// BM=128, BN=128 (2x 32 gate + 32 up), BK=32, 256 thr, 4 waves 2Mx2N.
// A bf16 + B fp32 both staged via global_load_lds (no staging VGPRs, no cvt in staging).
// LDS 48KB -> 3 blocks/CU. B converted fp32->bf16 at fragment read.
__global__ __launch_bounds__(256, 3) void moe_gemm1(
    const uint16_t* __restrict__ A1_perm, const float* __restrict__ w1,
    const int* __restrict__ offs, uint16_t* __restrict__ A_ws)
{
  const int s = blockIdx.x;            // 2816 = 88*4*8
  const int xcd = s & 7, kk = s >> 3;
  const int mt = kk & 3, pl = kk >> 2; // mt: 4 M-tiles of 128, same (e,ns) pack on one XCD
  const int pair = pl * 8 + xcd;       // 0..703
  const int e = pair / 22, ns = pair % 22;

  const int off = offs[e];
  const int cnt = min(offs[e + 1] - off, CAP);
  if (mt * 128 >= cnt) return;

  __shared__ __align__(16) char lds[49152];  // A 2x8KB @0 ; B(fp32) 2x16KB @16384
  const int tid = threadIdx.x;

  // A staging: round j: LDS row r=j*64+tid/4 (64B rows), slot s=tid&3; src chunk = s^((r>>1)&3)
  const uint16_t* asrc[2];
#pragma unroll
  for (int j = 0; j < 2; ++j) {
    int r = j * 64 + (tid >> 2);
    int srow = min(off + mt * 128 + r, TA - 1);     // dead rows guarded at epilogue
    int ss = (tid & 3) ^ ((r >> 1) & 3);
    asrc[j] = A1_perm + (size_t)srow * HIDDEN + ss * 8;
  }
  // B staging: round j: LDS row r=j*32+tid/8 (128B fp32 rows), slot s8=tid&7; src chunk = s8^(r&7)
  // col(r): q=(r>>5)&1 gate/up, wnh=r>>6, i=r&31 -> q*HALFI + ns*64 + wnh*32 + i
  const float* bsrc[4];
#pragma unroll
  for (int j = 0; j < 4; ++j) {
    int r = j * 32 + (tid >> 3);
    int q = (r >> 5) & 1, wnh = r >> 6, i = r & 31;
    int col = q * HALFI + ns * 64 + wnh * 32 + i;
    int ss = (tid & 7) ^ (r & 7);
    bsrc[j] = w1 + ((size_t)e * INTER + col) * HIDDEN + ss * 4;
  }
  const u32 dst16 = (u32)tid * 16;

  auto STAGE = [&](int buf, int k0) {
    char* ab = lds + buf * 8192;
    char* bb = lds + 16384 + buf * 16384;
#pragma unroll
    for (int j = 0; j < 4; ++j) gload16(bsrc[j] + k0, bb + j * 4096 + dst16);
#pragma unroll
    for (int j = 0; j < 2; ++j) gload16(asrc[j] + k0, ab + j * 4096 + dst16);
  };

  const int lane = tid & 63, wv = tid >> 6;
  const int wm = (wv >> 1) * 64, wn = wv & 1;
  const int fr = lane & 15, fq = lane >> 4;

  f32x4 acc[4][4];
#pragma unroll
  for (int i = 0; i < 4; ++i)
#pragma unroll
    for (int j = 0; j < 4; ++j) acc[i][j] = (f32x4)0.f;

  // fragment byte offsets (within current buf)
  u32 aoffr[4], bofflo[4], boffhi[4];
#pragma unroll
  for (int mf = 0; mf < 4; ++mf) {
    int r = wm + mf * 16 + fr;
    aoffr[mf] = (u32)(r * 64 + ((fq ^ ((r >> 1) & 3)) * 16));
  }
#pragma unroll
  for (int nf = 0; nf < 4; ++nf) {
    int r = wn * 64 + nf * 16 + fr;
    bofflo[nf] = (u32)(r * 128 + (((2 * fq) ^ (r & 7)) * 16));
    boffhi[nf] = (u32)(r * 128 + (((2 * fq + 1) ^ (r & 7)) * 16));
  }

  const int NT = HIDDEN / BK;  // 64
  STAGE(0, 0);
  int cur = 0;
  for (int t = 0; t < NT; ++t) {
    __syncthreads();                         // drains gloads -> buf[cur] ready
    if (t + 1 < NT) STAGE(cur ^ 1, (t + 1) * BK);
    const char* ab = lds + cur * 8192;
    const char* bb = lds + 16384 + cur * 16384;
    bf16x8 af[4];
#pragma unroll
    for (int mf = 0; mf < 4; ++mf) af[mf] = *(const bf16x8*)(ab + aoffr[mf]);
#pragma unroll
    for (int nf = 0; nf < 4; ++nf) {
      f32x4 lo = *(const f32x4*)(bb + bofflo[nf]);
      f32x4 hi = *(const f32x4*)(bb + boffhi[nf]);
      bf16x8 bfv = cvt8(lo, hi);
#pragma unroll
      for (int mf = 0; mf < 4; ++mf)
        acc[mf][nf] = __builtin_amdgcn_mfma_f32_16x16x32_bf16(af[mf], bfv, acc[mf][nf], 0, 0, 0);
    }
    cur ^= 1;
  }

  // epilogue: silu(gate nf0,1)*up(nf2,3) -> bf16 A_ws
#pragma unroll
  for (int mf = 0; mf < 4; ++mf) {
#pragma unroll
    for (int r = 0; r < 4; ++r) {
      int grow = mt * 128 + wm + mf * 16 + fq * 4 + r;
      if (grow < cnt) {
        size_t srow = (size_t)(off + grow);
#pragma unroll
        for (int nf = 0; nf < 2; ++nf) {
          float g = acc[mf][nf][r];
          float u = acc[mf][nf + 2][r];
          float val = g / (1.f + __expf(-g)) * u;
          A_ws[srow * HALFI + ns * 64 + wn * 32 + nf * 16 + fr] = bf16b(val);
        }
      }
    }
  }
}

// ---------------- GEMM2: Y = A_ws * W2^T (fp32 per assignment, no atomics) ----------------
__global__ __launch_bounds__(256, 3) void moe_gemm2(
    const uint16_t* __restrict__ A_ws, const float* __restrict__ w2,
    const int* __restrict__ offs, float* __restrict__ Y)
{
  const int s = blockIdx.x;            // 2048 = 64*4*8
  const int xcd = s & 7, kk = s >> 3;
  const int mt = kk & 3, pl = kk >> 2;
  const int pair = pl * 8 + xcd;       // 0..511
  const int e = pair >> 4, ns = pair & 15;

  const int off = offs[e];
  const int cnt = min(offs[e + 1] - off, CAP);
  if (mt * 128 >= cnt) return;

  __shared__ __align__(16) char lds[49152];
  const int tid = threadIdx.x;

  const uint16_t* asrc[2];
#pragma unroll
  for (int j = 0; j < 2; ++j) {
    int r = j * 64 + (tid >> 2);
    int srow = min(off + mt * 128 + r, TA - 1);
    int ss = (tid & 3) ^ ((r >> 1) & 3);
    asrc[j] = A_ws + (size_t)srow * HALFI + ss * 8;
  }
  const float* bsrc[4];
#pragma unroll
  for (int j = 0; j < 4; ++j) {
    int r = j * 32 + (tid >> 3);
    int col = ns * 128 + r;
    int ss = (tid & 7) ^ (r & 7);
    bsrc[j] = w2 + ((size_t)e * HIDDEN + col) * HALFI + ss * 4;
  }
  const u32 dst16 = (u32)tid * 16;

  auto STAGE = [&](int buf, int k0) {
    char* ab = lds + buf * 8192;
    char* bb = lds + 16384 + buf * 16384;
#pragma unroll
    for (int j = 0; j < 4; ++j) gload16(bsrc[j] + k0, bb + j * 4096 + dst16);
#pragma unroll
    for (int j = 0; j < 2; ++j) gload16(asrc[j] + k0, ab + j * 4096 + dst16);
  };

  const int lane = tid & 63, wv = tid >> 6;
  const int wm = (wv >> 1) * 64, wn = wv & 1;
  const int fr = lane & 15, fq = lane >> 4;

  f32x4 acc[4][4];
#pragma unroll
  for (int i = 0; i < 4; ++i)
#pragma unroll
    for (int j = 0; j < 4; ++j) acc[i][j] = (f32x4)0.f;

  u32 aoffr[4], bofflo[4], boffhi[4];
#pragma unroll
  for (int mf = 0; mf < 4; ++mf) {
    int r = wm + mf * 16 + fr;
    aoffr[mf] = (u32)(r * 64 + ((fq ^ ((r >> 1) & 3)) * 16));
  }
#pragma unroll
  for (int nf = 0; nf < 4; ++nf) {
    int r = wn * 64 + nf * 16 + fr;
    bofflo[nf] = (u32)(r * 128 + (((2 * fq) ^ (r & 7)) * 16));
    boffhi[nf] = (u32)(r * 128 + (((2 * fq + 1) ^ (r & 7)) * 16));
  }

  const int NT = HALFI / BK;  // 44
  STAGE(0, 0);
  int cur = 0;
  for (int t = 0; t < NT; ++t) {
    __syncthreads();
    if (t + 1 < NT) STAGE(cur ^ 1, (t + 1) * BK);
    const char* ab = lds + cur * 8192;
    const char* bb = lds + 16384 + cur * 16384;
    bf16x8 af[4];
#pragma unroll
    for (int mf = 0; mf < 4; ++mf) af[mf] = *(const bf16x8*)(ab + aoffr[mf]);
#pragma unroll
    for (int nf = 0; nf < 4; ++nf) {
      f32x4 lo = *(const f32x4*)(bb + bofflo[nf]);
      f32x4 hi = *(const f32x4*)(bb + boffhi[nf]);
      bf16x8 bfv = cvt8(lo, hi);
#pragma unroll
      for (int mf = 0; mf < 4; ++mf)
        acc[mf][nf] = __builtin_amdgcn_mfma_f32_16x16x32_bf16(af[mf], bfv, acc[mf][nf], 0, 0, 0);
    }
    cur ^= 1;
  }

#pragma unroll
  for (int mf = 0; mf < 4; ++mf) {
#pragma unroll
    for (int r = 0; r < 4; ++r) {
      int grow = mt * 128 + wm + mf * 16 + fq * 4 + r;
      if (grow < cnt) {
        size_t srow = (size_t)(off + grow);
        float* po = Y + srow * HIDDEN + ns * 128 + wn * 64 + fr;
#pragma unroll
        for (int nf = 0; nf < 4; ++nf)
          po[nf * 16] = acc[mf][nf][r];
      }
    }
  }
}

// ---------------- combine: out[tok] = sum_slot w[tok,slot] * Y[inv[tok,slot]] ----------------
__global__ __launch_bounds__(256) void combine(
    const float* __restrict__ Y, const float* __restrict__ tkw,
    const int* __restrict__ inv, float* __restrict__ out) {
  const int tok = blockIdx.x;
  const int c = threadIdx.x * 8;
  f32x4 s0 = (f32x4)0.f, s1 = (f32x4)0.f;
#pragma unroll
  for (int slot = 0; slot < TOPK; ++slot) {
    int srow = inv[tok * TOPK + slot];
    if (srow >= 0) {
      float w = tkw[tok * TOPK + slot];
      const float* y = Y + (size_t)srow * HIDDEN + c;
      f32x4 a = *(const f32x4*)y;
      f32x4 b = *(const f32x4*)(y + 4);
      s0 += w * a;
      s1 += w * b;
    }
  }
  float* po = out + (size_t)tok * HIDDEN + c;
  *(f32x4*)po = s0;
  *(f32x4*)(po + 4) = s1;
}

extern "C" void kernel_launch(void* const* d_in, const int* in_sizes, int n_in,
                              void* d_out, int out_size, void* d_ws, size_t ws_size,
                              hipStream_t stream) {
  const float* hidden = (const float*)d_in[0];
  const float* topk_w = (const float*)d_in[1];
  const float* w1     = (const float*)d_in[2];
  const float* w2     = (const float*)d_in[3];
  const int*   tkidx  = (const int*)d_in[4];

  char* ws = (char*)d_ws;
  int*      offs       = (int*)ws;                          // 33 ints
  int*      tok_of_row = (int*)(ws + 1024);                 // TA ints
  int*      inv        = (int*)(ws + 1024 + 4 * TA);        // TA ints
  uint16_t* A1_perm    = (uint16_t*)(ws + 131072);          // TA x 2048 bf16 (33.5 MB)
  uint16_t* A_ws       = (uint16_t*)(ws + 131072 + (size_t)TA * HIDDEN * 2);          // TA x 1408 bf16
  float*    Y          = (float*)(ws + 131072 + (size_t)TA * (HIDDEN + HALFI) * 2);   // TA x 2048 f32
  float*    out        = (float*)d_out;

  route_count<<<1, 256, 0, stream>>>(tkidx, offs);
  route_build<<<NUM_EXPERTS, 64, 0, stream>>>(tkidx, topk_w, offs, tok_of_row, inv);
  perm_cast<<<TA, 256, 0, stream>>>(hidden, tok_of_row, A1_perm);
  moe_gemm1<<<dim3(22 * 32 * 4), 256, 0, stream>>>(A1_perm, w1, offs, A_ws);
  moe_gemm2<<<dim3(16 * 32 * 4), 256, 0, stream>>>(A_ws, w2, offs, Y);
  combine<<<TOKENS, 256, 0, stream>>>(Y, topk_w, inv, out);
}